// Round 1
// baseline (23.950 us; speedup 1.0000x reference)
//
#include <hip/hip_runtime.h>
#include <math.h>

namespace {

constexpr int NB = 8;     // batch
constexpr int NS = 48;    // samples
constexpr int NA = 8192;  // atoms
constexpr int BSIZE = 256;

// ws layout (floats):
// [0 .. NB*8)                 per-b: wsum, St0, St1, St2, Stt, msum  (6 used of 8)
// [64 .. 64 + NB*NS*16)       per-(b,s): Spp, Sp0, Sp1, Sp2, H[9]   (13 used of 16)

template <int CNT>
__device__ inline void blockReduceWrite(const float (&v)[CNT], float* __restrict__ dst,
                                        float* lds, int nwaves) {
  const int lane = threadIdx.x & 63;
  const int wave = threadIdx.x >> 6;
#pragma unroll
  for (int k = 0; k < CNT; ++k) {
    float x = v[k];
#pragma unroll
    for (int off = 32; off; off >>= 1) x += __shfl_xor(x, off, 64);
    if (lane == 0) lds[wave * CNT + k] = x;
  }
  __syncthreads();
  if ((int)threadIdx.x < CNT) {
    float s = 0.f;
    for (int w = 0; w < nwaves; ++w) s += lds[w * CNT + threadIdx.x];
    dst[threadIdx.x] = s;
  }
}

__global__ __launch_bounds__(BSIZE) void reduce_kernel(
    const float* __restrict__ pred, const float* __restrict__ truec,
    const int* __restrict__ mask, const int* __restrict__ dna,
    const int* __restrict__ rna, const int* __restrict__ lig,
    float* __restrict__ ws) {
  __shared__ float lds[(BSIZE / 64) * 13];
  const int blk = blockIdx.x;

  if (blk < NB * NS) {
    const int b = blk / NS;
    const float* p = pred + (size_t)blk * NA * 3;
    const float* t = truec + (size_t)b * NA * 3;
    const int base = b * NA;

    float acc[13];
#pragma unroll
    for (int k = 0; k < 13; ++k) acc[k] = 0.f;

    auto atom = [&](float w, float p0, float p1, float p2, float t0, float t1, float t2) {
      const float w0 = w * p0, w1 = w * p1, w2 = w * p2;
      acc[0] += w0 * p0 + w1 * p1 + w2 * p2;
      acc[1] += w0;
      acc[2] += w1;
      acc[3] += w2;
      acc[4] += w0 * t0;
      acc[5] += w0 * t1;
      acc[6] += w0 * t2;
      acc[7] += w1 * t0;
      acc[8] += w1 * t1;
      acc[9] += w1 * t2;
      acc[10] += w2 * t0;
      acc[11] += w2 * t1;
      acc[12] += w2 * t2;
    };
    auto wgt = [](int m, int d, int r, int l) {
      return (1.0f + 5.0f * (float)d + 5.0f * (float)r + 10.0f * (float)l) * (float)m;
    };

    for (int it = 0; it < NA / (BSIZE * 4); ++it) {
      const int n0 = it * BSIZE * 4 + threadIdx.x * 4;  // 4 atoms / thread / iter
      const float4 pa = *(const float4*)(p + 3 * n0);
      const float4 pb = *(const float4*)(p + 3 * n0 + 4);
      const float4 pc = *(const float4*)(p + 3 * n0 + 8);
      const float4 ta = *(const float4*)(t + 3 * n0);
      const float4 tb = *(const float4*)(t + 3 * n0 + 4);
      const float4 tc = *(const float4*)(t + 3 * n0 + 8);
      const int4 mk = *(const int4*)(mask + base + n0);
      const int4 dn = *(const int4*)(dna + base + n0);
      const int4 rn = *(const int4*)(rna + base + n0);
      const int4 lg = *(const int4*)(lig + base + n0);

      atom(wgt(mk.x, dn.x, rn.x, lg.x), pa.x, pa.y, pa.z, ta.x, ta.y, ta.z);
      atom(wgt(mk.y, dn.y, rn.y, lg.y), pa.w, pb.x, pb.y, ta.w, tb.x, tb.y);
      atom(wgt(mk.z, dn.z, rn.z, lg.z), pb.z, pb.w, pc.x, tb.z, tb.w, tc.x);
      atom(wgt(mk.w, dn.w, rn.w, lg.w), pc.y, pc.z, pc.w, tc.y, tc.z, tc.w);
    }
    blockReduceWrite<13>(acc, ws + 64 + blk * 16, lds, BSIZE / 64);
  } else {
    // per-b sums
    const int b = blk - NB * NS;
    const float* t = truec + (size_t)b * NA * 3;
    const int base = b * NA;

    float acc[6];
#pragma unroll
    for (int k = 0; k < 6; ++k) acc[k] = 0.f;

    auto atomb = [&](int m, int d, int r, int l, float t0, float t1, float t2) {
      const float mf = (float)m;
      const float w = (1.0f + 5.0f * (float)d + 5.0f * (float)r + 10.0f * (float)l) * mf;
      acc[0] += w;
      acc[1] += w * t0;
      acc[2] += w * t1;
      acc[3] += w * t2;
      acc[4] += w * (t0 * t0 + t1 * t1 + t2 * t2);
      acc[5] += mf;
    };

    for (int it = 0; it < NA / (BSIZE * 4); ++it) {
      const int n0 = it * BSIZE * 4 + threadIdx.x * 4;
      const float4 ta = *(const float4*)(t + 3 * n0);
      const float4 tb = *(const float4*)(t + 3 * n0 + 4);
      const float4 tc = *(const float4*)(t + 3 * n0 + 8);
      const int4 mk = *(const int4*)(mask + base + n0);
      const int4 dn = *(const int4*)(dna + base + n0);
      const int4 rn = *(const int4*)(rna + base + n0);
      const int4 lg = *(const int4*)(lig + base + n0);

      atomb(mk.x, dn.x, rn.x, lg.x, ta.x, ta.y, ta.z);
      atomb(mk.y, dn.y, rn.y, lg.y, ta.w, tb.x, tb.y);
      atomb(mk.z, dn.z, rn.z, lg.z, tb.z, tb.w, tc.x);
      atomb(mk.w, dn.w, rn.w, lg.w, tc.y, tc.z, tc.w);
    }
    blockReduceWrite<6>(acc, ws + b * 8, lds, BSIZE / 64);
  }
}

__global__ __launch_bounds__(NB * NS) void final_kernel(const float* __restrict__ ws,
                                                        const float* __restrict__ scale,
                                                        float* __restrict__ out) {
  const int tid = threadIdx.x;  // 0 .. 383, tid = b*NS + s
  const int b = tid / NS;

  const float* pb = ws + b * 8;
  const double wsum = (double)pb[0];
  const double st0 = (double)pb[1], st1 = (double)pb[2], st2 = (double)pb[3];
  const double stt = (double)pb[4];
  const double msum = (double)pb[5];

  const float* ps = ws + 64 + tid * 16;
  const double spp = (double)ps[0];
  const double sp0 = (double)ps[1], sp1 = (double)ps[2], sp2 = (double)ps[3];

  const double inv = 1.0 / wsum;
  const double Sp[3] = {sp0, sp1, sp2};
  const double St[3] = {st0, st1, st2};

  double H[3][3];
#pragma unroll
  for (int i = 0; i < 3; ++i)
#pragma unroll
    for (int j = 0; j < 3; ++j) H[i][j] = (double)ps[4 + 3 * i + j] - Sp[i] * St[j] * inv;

  const double Sq = spp - (sp0 * sp0 + sp1 * sp1 + sp2 * sp2) * inv;
  const double Sy = stt - (st0 * st0 + st1 * st1 + st2 * st2) * inv;

  // K = H^T H  (symmetric PSD)
  double K[3][3];
#pragma unroll
  for (int i = 0; i < 3; ++i)
#pragma unroll
    for (int j = 0; j < 3; ++j)
      K[i][j] = H[0][i] * H[0][j] + H[1][i] * H[1][j] + H[2][i] * H[2][j];

  // closed-form eigenvalues of symmetric 3x3
  const double q = (K[0][0] + K[1][1] + K[2][2]) / 3.0;
  const double p1 = K[0][1] * K[0][1] + K[0][2] * K[0][2] + K[1][2] * K[1][2];
  const double a0 = K[0][0] - q, a1 = K[1][1] - q, a2 = K[2][2] - q;
  const double p2 = a0 * a0 + a1 * a1 + a2 * a2 + 2.0 * p1;
  double e1, e2, e3;
  if (p2 <= 1e-300) {
    e1 = e2 = e3 = q;
  } else {
    const double pp = sqrt(p2 / 6.0);
    const double ip = 1.0 / pp;
    const double B00 = a0 * ip, B11 = a1 * ip, B22 = a2 * ip;
    const double B01 = K[0][1] * ip, B02 = K[0][2] * ip, B12 = K[1][2] * ip;
    double r = 0.5 * (B00 * (B11 * B22 - B12 * B12) - B01 * (B01 * B22 - B12 * B02) +
                      B02 * (B01 * B12 - B11 * B02));
    r = fmin(1.0, fmax(-1.0, r));
    const double phi = acos(r) / 3.0;
    e1 = q + 2.0 * pp * cos(phi);
    e3 = q + 2.0 * pp * cos(phi + 2.0943951023931953);  // + 2*pi/3 -> smallest
    e2 = 3.0 * q - e1 - e3;
  }
  const double s1 = sqrt(fmax(e1, 0.0));
  const double s2 = sqrt(fmax(e2, 0.0));
  const double s3 = sqrt(fmax(e3, 0.0));  // smallest singular value

  const double detH =
      H[0][0] * (H[1][1] * H[2][2] - H[1][2] * H[2][1]) -
      H[0][1] * (H[1][0] * H[2][2] - H[1][2] * H[2][0]) +
      H[0][2] * (H[1][0] * H[2][1] - H[1][1] * H[2][0]);
  const double d = (detH > 0.0) ? 1.0 : ((detH < 0.0) ? -1.0 : 0.0);

  const double trRtH = s1 + s2 + d * s3;
  const double cost = Sq + Sy - 2.0 * trRtH;
  const double denom = msum + 1e-6;
  const double per_sample = cost / denom * (double)scale[tid];

  // loss = mean_b( (1/3) * mean_s(per_sample) )
  double c = per_sample * (1.0 / (3.0 * (double)NS * (double)NB));

#pragma unroll
  for (int off = 32; off; off >>= 1) c += __shfl_xor(c, off, 64);

  __shared__ double lds[NB * NS / 64];
  if ((tid & 63) == 0) lds[tid >> 6] = c;
  __syncthreads();
  if (tid == 0) {
    double s = 0.0;
    for (int w = 0; w < NB * NS / 64; ++w) s += lds[w];
    out[0] = (float)s;
  }
}

}  // namespace

extern "C" void kernel_launch(void* const* d_in, const int* in_sizes, int n_in,
                              void* d_out, int out_size, void* d_ws, size_t ws_size,
                              hipStream_t stream) {
  const float* pred = (const float*)d_in[0];
  const float* truec = (const float*)d_in[1];
  const int* mask = (const int*)d_in[2];
  const int* dna = (const int*)d_in[3];
  const int* rna = (const int*)d_in[4];
  const int* lig = (const int*)d_in[5];
  const float* scale = (const float*)d_in[6];
  float* ws = (float*)d_ws;
  float* out = (float*)d_out;

  reduce_kernel<<<NB * NS + NB, BSIZE, 0, stream>>>(pred, truec, mask, dna, rna, lig, ws);
  final_kernel<<<1, NB * NS, 0, stream>>>(ws, scale, out);
}